// Round 2
// baseline (1858.674 us; speedup 1.0000x reference)
//
#include <hip/hip_runtime.h>

#define TS 32
#define NN 1024
#define FF 64
#define HH 128
#define H4 512
#define KC 384   // 3*HH, concat K for [Wx;Wn;Wh]

typedef __attribute__((ext_vector_type(8))) short bf16x8;
typedef __attribute__((ext_vector_type(4))) float f32x4;
typedef __attribute__((ext_vector_type(4))) short s16x4;

static __device__ __forceinline__ float bf2f(short s) {
    union { unsigned int u; float f; } v;
    v.u = ((unsigned int)(unsigned short)s) << 16;
    return v.f;
}
static __device__ __forceinline__ short f2bf(float x) {   // RTNE
    union { float f; unsigned int u; } v; v.f = x;
    unsigned int r = v.u + 0x7fffu + ((v.u >> 16) & 1u);
    return (short)(r >> 16);
}
static __device__ __forceinline__ bf16x8 cvt8(const float* p) {
    f32x4 lo = *(const f32x4*)p;
    f32x4 hi = *(const f32x4*)(p + 4);
    bf16x8 r;
#pragma unroll
    for (int j = 0; j < 4; j++) { r[j] = f2bf(lo[j]); r[4 + j] = f2bf(hi[j]); }
    return r;
}
static __device__ __forceinline__ float ldf(const void* p, int i, int F32) {
    return F32 ? ((const float*)p)[i] : bf2f(((const short*)p)[i]);
}
static __device__ __forceinline__ float sigm(float x) { return 1.0f / (1.0f + __expf(-x)); }
static __device__ __forceinline__ float tanhfast(float x) { return 1.0f - 2.0f / (__expf(2.0f * x) + 1.0f); }
static __device__ __forceinline__ f32x4 MFMA(bf16x8 a, bf16x8 b, f32x4 c) {
    return __builtin_amdgcn_mfma_f32_16x16x32_bf16(a, b, c, 0, 0, 0);
}

// ------------- dtype detector: true f32 N(0,1) has exponent field in [90,160] -------
__global__ __launch_bounds__(64) void k_detect(const unsigned int* __restrict__ xbits,
                                               int* __restrict__ flag) {
    const int lane = threadIdx.x;
    int cnt = 0;
    for (int i = lane; i < 1024; i += 64) {
        const unsigned e = (xbits[i] >> 23) & 0xffu;
        cnt += (e >= 90u && e <= 160u) ? 1 : 0;
    }
#pragma unroll
    for (int off = 32; off > 0; off >>= 1) cnt += __shfl_down(cnt, off, 64);
    if (lane == 0) flag[0] = (cnt >= 768) ? 1 : 0;
}

// ---------------- xs = x @ Win^T + Win_b  (MFMA) ------------------------------------
__global__ __launch_bounds__(256) void k_xs(const void* __restrict__ xv,
                                            const void* __restrict__ winw,
                                            const void* __restrict__ winb,
                                            short* __restrict__ xs,
                                            const int* __restrict__ flag) {
    const int F32 = *flag;
    const float* xf = (const float*)xv;  const short* xh = (const short*)xv;
    const float* wf = (const float*)winw; const short* wh = (const short*)winw;
    const int wv = threadIdx.x >> 6, lane = threadIdx.x & 63;
    const int quad = lane >> 4, l16 = lane & 15;
    const int row0 = blockIdx.x * 64 + wv * 16;   // 512 blocks x 64 rows = T*N
    f32x4 acc[8];
#pragma unroll
    for (int i = 0; i < 8; i++) acc[i] = (f32x4){0.f, 0.f, 0.f, 0.f};
#pragma unroll
    for (int kt = 0; kt < 2; kt++) {
        const int k = kt * 32 + quad * 8;
        const size_t aoff = (size_t)(row0 + l16) * FF + k;
        bf16x8 a = F32 ? cvt8(xf + aoff) : *(const bf16x8*)(xh + aoff);
#pragma unroll
        for (int nt = 0; nt < 8; nt++) {
            const size_t boff = (size_t)(nt * 16 + l16) * FF + k;
            bf16x8 b = F32 ? cvt8(wf + boff) : *(const bf16x8*)(wh + boff);
            acc[nt] = MFMA(a, b, acc[nt]);
        }
    }
#pragma unroll
    for (int nt = 0; nt < 8; nt++) {
        const int hcol = nt * 16 + l16;
        const float bias = ldf(winb, hcol, F32);
#pragma unroll
        for (int r = 0; r < 4; r++) {
            const int row = row0 + quad * 4 + r;
            xs[(size_t)row * HH + hcol] = f2bf(acc[nt][r] + bias);
        }
    }
}

// ---------------- init carries: h=c=xs[0] (fwd) / xs[T-1] (bwd); also transposed hT ---
__global__ __launch_bounds__(256) void k_init(const short* __restrict__ xs,
                                              short* hf, short* hTf, float* cf,
                                              short* hb, short* hTb, float* cb) {
    const int idx = blockIdx.x * 256 + threadIdx.x;
    const int dir = idx >> 17;
    const int rem = idx & 131071;
    const int row = rem >> 7, hcol = rem & 127;
    const int frame = dir ? (TS - 1) : 0;
    const short v = xs[((size_t)frame * NN + row) * HH + hcol];
    short* h_rm = dir ? hb : hf;
    short* hT   = dir ? hTb : hTf;
    float* c    = dir ? cb : cf;
    h_rm[rem] = v;
    hT[hcol * NN + row] = v;
    c[rem] = bf2f(v);
}

// ---------------- transpose [Wx;Wn;Wh] (384 x 512) -> WcatT (512 x 384) bf16 --------
__global__ __launch_bounds__(256) void k_wprep(const void* __restrict__ Wx,
                                               const void* __restrict__ Wn,
                                               const void* __restrict__ Wh,
                                               short* __restrict__ WcatT,
                                               const int* __restrict__ flag) {
    const int F32 = *flag;
    __shared__ __align__(16) short tile[64][72];
    const int b = blockIdx.x;              // 48 blocks: 8 (n) x 6 (k)
    const int n0 = (b / 6) * 64, k0 = (b % 6) * 64;
    for (int i = threadIdx.x; i < 512; i += 256) {
        const int r = i >> 3, cc = i & 7;
        const int kg = k0 + r;
        const void* m = (kg < 128) ? Wx : (kg < 256 ? Wn : Wh);
        const size_t off = (size_t)(kg & 127) * H4 + n0 + cc * 8;
        *(bf16x8*)&tile[r][cc * 8] =
            F32 ? cvt8((const float*)m + off) : *(const bf16x8*)((const short*)m + off);
    }
    __syncthreads();
    for (int i = threadIdx.x; i < 512; i += 256) {
        const int rr = i >> 3, kk = i & 7;
        bf16x8 o;
#pragma unroll
        for (int j = 0; j < 8; j++) o[j] = tile[kk * 8 + j][rr];
        *(bf16x8*)(WcatT + (size_t)(n0 + rr) * KC + k0 + kk * 8) = o;
    }
}

// ---------------- one full timestep (both dirs, both GNN layers, gating) ------------
__global__ __launch_bounds__(256, 2) void k_step(
    const void* __restrict__ adjs, const short* __restrict__ xs,
    const short* __restrict__ WcT_f, const short* __restrict__ WcT_b,
    const void* __restrict__ bias_f, const void* __restrict__ bias_b,
    short* __restrict__ hf, short* __restrict__ hb,
    const short* __restrict__ hTin_f, const short* __restrict__ hTin_b,
    short* __restrict__ hTout_f, short* __restrict__ hTout_b,
    float* __restrict__ cf, float* __restrict__ cb, int t,
    const int* __restrict__ flag) {
    const int F32 = *flag;
    const int dir = blockIdx.x >> 5;
    const int R = (blockIdx.x & 31) * 32;
    const int tid = threadIdx.x;
    const int wv = tid >> 6, lane = tid & 63;
    const int quad = lane >> 4, l16 = lane & 15;
    const int frame = dir ? (TS - 1 - t) : t;
    const float* adjf = (const float*)adjs + (size_t)frame * NN * NN;
    const short* adjh = (const short*)adjs + (size_t)frame * NN * NN;
    const short* xs_t  = xs + (size_t)frame * NN * HH;
    const short* WcT   = dir ? WcT_b : WcT_f;
    const void* bias   = dir ? bias_b : bias_f;
    short* h_rm        = dir ? hb : hf;
    const short* hT_in = dir ? hTin_b : hTin_f;
    short* hT_out      = dir ? hTout_b : hTout_f;
    float* c_g         = dir ? cb : cf;

    // Acat rows = 32 local rows; cols: [0,128)=xs_t, [128,256)=n, [256,384)=h_l
    __shared__ __align__(16) short Acat[32][392];   // +8 pad: conflict-free ds_read_b128
    __shared__ __align__(16) short adjT[32][136];

    for (int i = tid; i < 512; i += 256) {
        const int r = i >> 4, cc = i & 15;
        *(bf16x8*)&Acat[r][cc * 8]       = *(const bf16x8*)(xs_t + (size_t)(R + r) * HH + cc * 8);
        *(bf16x8*)&Acat[r][256 + cc * 8] = *(const bf16x8*)(h_rm + (size_t)(R + r) * HH + cc * 8);
    }

    // ---- phase 1: n_R = adj[t][R:R+32, :] @ h_time   (B-frags straight from hT) ----
    f32x4 an[2][2];
#pragma unroll
    for (int a = 0; a < 2; a++)
#pragma unroll
        for (int b = 0; b < 2; b++) an[a][b] = (f32x4){0.f, 0.f, 0.f, 0.f};

    for (int kc = 0; kc < 8; kc++) {
        __syncthreads();
        for (int i = tid; i < 512; i += 256) {
            const int r = i >> 4, cc = i & 15;
            const size_t off = (size_t)(R + r) * NN + kc * 128 + cc * 8;
            *(bf16x8*)&adjT[r][cc * 8] =
                F32 ? cvt8(adjf + off) : *(const bf16x8*)(adjh + off);
        }
        __syncthreads();
#pragma unroll
        for (int ki = 0; ki < 4; ki++) {
            const int kk = ki * 32 + quad * 8;
            bf16x8 a0 = *(const bf16x8*)&adjT[l16][kk];
            bf16x8 a1 = *(const bf16x8*)&adjT[16 + l16][kk];
#pragma unroll
            for (int nj = 0; nj < 2; nj++) {
                const int hrow = (2 * wv + nj) * 16 + l16;
                bf16x8 b = *(const bf16x8*)(hT_in + hrow * NN + kc * 128 + kk);
                an[0][nj] = MFMA(a0, b, an[0][nj]);
                an[1][nj] = MFMA(a1, b, an[1][nj]);
            }
        }
    }
    __syncthreads();
#pragma unroll
    for (int mt = 0; mt < 2; mt++)
#pragma unroll
        for (int nj = 0; nj < 2; nj++) {
            const int hcol = (2 * wv + nj) * 16 + l16;
#pragma unroll
            for (int r = 0; r < 4; r++)
                Acat[mt * 16 + quad * 4 + r][128 + hcol] = f2bf(an[mt][nj][r]);
        }
    __syncthreads();

    // ---- phase 2: two GNN layers. z = Acat @ Wcat + b; gate; update h region ------
    float creg[2][2][4];
#pragma unroll
    for (int l = 0; l < 2; l++) {
        f32x4 az[2][4][2];   // [mt][gate][st]; wave wv owns h-cols [wv*32, wv*32+32)
#pragma unroll
        for (int m = 0; m < 2; m++)
#pragma unroll
            for (int g = 0; g < 4; g++)
#pragma unroll
                for (int s = 0; s < 2; s++) az[m][g][s] = (f32x4){0.f, 0.f, 0.f, 0.f};

        for (int kt = 0; kt < 12; kt++) {
            const int kk = kt * 32 + quad * 8;
            bf16x8 a0 = *(const bf16x8*)&Acat[l16][kk];
            bf16x8 a1 = *(const bf16x8*)&Acat[16 + l16][kk];
#pragma unroll
            for (int gt = 0; gt < 4; gt++)
#pragma unroll
                for (int st = 0; st < 2; st++) {
                    const int ncol = gt * 128 + wv * 32 + st * 16 + l16;
                    bf16x8 b = *(const bf16x8*)(WcT + (size_t)ncol * KC + kk);
                    az[0][gt][st] = MFMA(a0, b, az[0][gt][st]);
                    az[1][gt][st] = MFMA(a1, b, az[1][gt][st]);
                }
        }

        short hbf[2][2][4];
#pragma unroll
        for (int mt = 0; mt < 2; mt++)
#pragma unroll
            for (int st = 0; st < 2; st++) {
                const int hcol = wv * 32 + st * 16 + l16;
                const float bi  = ldf(bias, hcol, F32);
                const float bfv = ldf(bias, 128 + hcol, F32);
                const float bo  = ldf(bias, 256 + hcol, F32);
                const float bg  = ldf(bias, 384 + hcol, F32);
#pragma unroll
                for (int r = 0; r < 4; r++) {
                    const int grow = R + mt * 16 + quad * 4 + r;
                    const float zi = az[mt][0][st][r] + bi;
                    const float zf = az[mt][1][st][r] + bfv;
                    const float zo = az[mt][2][st][r] + bo;
                    const float zg = az[mt][3][st][r] + bg;
                    const float cold = (l == 0) ? c_g[(size_t)grow * HH + hcol] : creg[mt][st][r];
                    const float cn = sigm(zf) * cold + sigm(zi) * tanhfast(zg);
                    creg[mt][st][r] = cn;
                    hbf[mt][st][r] = f2bf(sigm(zo) * tanhfast(cn));
                }
            }
        if (l == 0) {
            __syncthreads();   // all waves done reading Acat h-region
#pragma unroll
            for (int mt = 0; mt < 2; mt++)
#pragma unroll
                for (int st = 0; st < 2; st++)
#pragma unroll
                    for (int r = 0; r < 4; r++)
                        Acat[mt * 16 + quad * 4 + r][256 + wv * 32 + st * 16 + l16] =
                            hbf[mt][st][r];
            __syncthreads();
        } else {
#pragma unroll
            for (int mt = 0; mt < 2; mt++)
#pragma unroll
                for (int st = 0; st < 2; st++) {
                    const int hcol = wv * 32 + st * 16 + l16;
                    s16x4 pk;
#pragma unroll
                    for (int r = 0; r < 4; r++) {
                        const int grow = R + mt * 16 + quad * 4 + r;
                        h_rm[(size_t)grow * HH + hcol] = hbf[mt][st][r];
                        c_g[(size_t)grow * HH + hcol] = creg[mt][st][r];
                        pk[r] = hbf[mt][st][r];
                    }
                    *(s16x4*)(hT_out + hcol * NN + R + mt * 16 + quad * 4) = pk;
                }
        }
    }
}

// ---------------- epilogue: y = (cat(hf,hb) @ fc0^T + fc0_b) @ wout^T + wout_b ------
__global__ __launch_bounds__(256) void k_epi(const short* __restrict__ hf,
                                             const short* __restrict__ hb,
                                             const void* __restrict__ fc0_w,
                                             const void* __restrict__ fc0_b,
                                             const void* __restrict__ wout_w,
                                             const void* __restrict__ wout_b,
                                             void* __restrict__ out,
                                             const int* __restrict__ flag) {
    const int F32 = *flag;
    __shared__ float v[256];
    const int tid = threadIdx.x;
    float a = 0.f;
    for (int j = 0; j < 128; j++) a += ldf(wout_w, j, F32) * ldf(fc0_w, j * 256 + tid, F32);
    v[tid] = a;
    __syncthreads();
    float s0 = ldf(wout_b, 0, F32);
    for (int j = 0; j < 128; j++) s0 += ldf(wout_w, j, F32) * ldf(fc0_b, j, F32);
    const int row = blockIdx.x * 256 + tid;
    float y = s0;
    for (int k = 0; k < 128; k++) y += bf2f(hf[(size_t)row * HH + k]) * v[k];
    for (int k = 0; k < 128; k++) y += bf2f(hb[(size_t)row * HH + k]) * v[128 + k];
    if (F32) ((float*)out)[row] = y;
    else ((short*)out)[row] = f2bf(y);
}

extern "C" void kernel_launch(void* const* d_in, const int* in_sizes, int n_in,
                              void* d_out, int out_size, void* d_ws, size_t ws_size,
                              hipStream_t stream) {
    const void* x      = d_in[0];
    const void* adjs   = d_in[1];
    const void* win_w  = d_in[3];
    const void* win_b  = d_in[4];
    const void* fWx    = d_in[5];
    const void* fWh    = d_in[6];
    const void* fWn    = d_in[7];
    const void* fb     = d_in[8];
    const void* bWx    = d_in[9];
    const void* bWh    = d_in[10];
    const void* bWn    = d_in[11];
    const void* bb     = d_in[12];
    const void* fc0_w  = d_in[13];
    const void* fc0_b  = d_in[14];
    const void* wout_w = d_in[15];
    const void* wout_b = d_in[16];

    char* ws = (char*)d_ws;
    size_t off = 0;
    auto alloc = [&](size_t bytes) -> void* {
        void* p = ws + off;
        off += (bytes + 255) & ~(size_t)255;
        return p;
    };
    int*   flag    = (int*)alloc(256);
    short* xs      = (short*)alloc((size_t)TS * NN * HH * 2);
    short* WcatT_f = (short*)alloc((size_t)H4 * KC * 2);
    short* WcatT_b = (short*)alloc((size_t)H4 * KC * 2);
    short* hf      = (short*)alloc((size_t)NN * HH * 2);
    short* hb      = (short*)alloc((size_t)NN * HH * 2);
    short* hTf0    = (short*)alloc((size_t)HH * NN * 2);
    short* hTf1    = (short*)alloc((size_t)HH * NN * 2);
    short* hTb0    = (short*)alloc((size_t)HH * NN * 2);
    short* hTb1    = (short*)alloc((size_t)HH * NN * 2);
    float* cf      = (float*)alloc((size_t)NN * HH * 4);
    float* cb      = (float*)alloc((size_t)NN * HH * 4);

    hipLaunchKernelGGL(k_detect, dim3(1), dim3(64), 0, stream, (const unsigned int*)x, flag);
    hipLaunchKernelGGL(k_wprep, dim3(48), dim3(256), 0, stream, fWx, fWn, fWh, WcatT_f, flag);
    hipLaunchKernelGGL(k_wprep, dim3(48), dim3(256), 0, stream, bWx, bWn, bWh, WcatT_b, flag);
    hipLaunchKernelGGL(k_xs, dim3(512), dim3(256), 0, stream, x, win_w, win_b, xs, flag);
    hipLaunchKernelGGL(k_init, dim3(1024), dim3(256), 0, stream, xs, hf, hTf0, cf, hb, hTb0, cb);
    for (int t = 0; t < TS; t++) {
        const short* hin_f = (t & 1) ? hTf1 : hTf0;
        short* hout_f      = (t & 1) ? hTf0 : hTf1;
        const short* hin_b = (t & 1) ? hTb1 : hTb0;
        short* hout_b      = (t & 1) ? hTb0 : hTb1;
        hipLaunchKernelGGL(k_step, dim3(64), dim3(256), 0, stream, adjs, xs,
                           WcatT_f, WcatT_b, fb, bb, hf, hb,
                           hin_f, hin_b, hout_f, hout_b, cf, cb, t, flag);
    }
    hipLaunchKernelGGL(k_epi, dim3(4), dim3(256), 0, stream, hf, hb, fc0_w, fc0_b,
                       wout_w, wout_b, d_out, flag);
}

// Round 3
// 1378.927 us; speedup vs baseline: 1.3479x; 1.3479x over previous
//
#include <hip/hip_runtime.h>

#define TS 32
#define NN 1024
#define FF 64
#define HH 128
#define H4 512
#define KC 384   // 3*HH, concat K for [Wx;Wn;Wh]

typedef __attribute__((ext_vector_type(8))) short bf16x8;
typedef __attribute__((ext_vector_type(4))) float f32x4;
typedef __attribute__((ext_vector_type(4))) short s16x4;

static __device__ __forceinline__ float bf2f(short s) {
    union { unsigned int u; float f; } v;
    v.u = ((unsigned int)(unsigned short)s) << 16;
    return v.f;
}
static __device__ __forceinline__ short f2bf(float x) {   // RTNE
    union { float f; unsigned int u; } v; v.f = x;
    unsigned int r = v.u + 0x7fffu + ((v.u >> 16) & 1u);
    return (short)(r >> 16);
}
static __device__ __forceinline__ bf16x8 cvt8(const float* p) {
    f32x4 lo = *(const f32x4*)p;
    f32x4 hi = *(const f32x4*)(p + 4);
    bf16x8 r;
#pragma unroll
    for (int j = 0; j < 4; j++) { r[j] = f2bf(lo[j]); r[4 + j] = f2bf(hi[j]); }
    return r;
}
static __device__ __forceinline__ float ldf(const void* p, int i, int F32) {
    return F32 ? ((const float*)p)[i] : bf2f(((const short*)p)[i]);
}
static __device__ __forceinline__ float sigm(float x) { return 1.0f / (1.0f + __expf(-x)); }
static __device__ __forceinline__ float tanhfast(float x) { return 1.0f - 2.0f / (__expf(2.0f * x) + 1.0f); }
static __device__ __forceinline__ f32x4 MFMA(bf16x8 a, bf16x8 b, f32x4 c) {
    return __builtin_amdgcn_mfma_f32_16x16x32_bf16(a, b, c, 0, 0, 0);
}

// ------------- dtype detector: true f32 N(0,1) has exponent field in [90,160] -------
__global__ __launch_bounds__(64) void k_detect(const unsigned int* __restrict__ xbits,
                                               int* __restrict__ flag) {
    const int lane = threadIdx.x;
    int cnt = 0;
    for (int i = lane; i < 1024; i += 64) {
        const unsigned e = (xbits[i] >> 23) & 0xffu;
        cnt += (e >= 90u && e <= 160u) ? 1 : 0;
    }
#pragma unroll
    for (int off = 32; off > 0; off >>= 1) cnt += __shfl_down(cnt, off, 64);
    if (lane == 0) flag[0] = (cnt >= 768) ? 1 : 0;
}

// ---------------- xs = x @ Win^T + Win_b  (MFMA) ------------------------------------
__global__ __launch_bounds__(256) void k_xs(const void* __restrict__ xv,
                                            const void* __restrict__ winw,
                                            const void* __restrict__ winb,
                                            short* __restrict__ xs,
                                            const int* __restrict__ flag) {
    const int F32 = *flag;
    const float* xf = (const float*)xv;  const short* xh = (const short*)xv;
    const float* wf = (const float*)winw; const short* wh = (const short*)winw;
    const int wv = threadIdx.x >> 6, lane = threadIdx.x & 63;
    const int quad = lane >> 4, l16 = lane & 15;
    const int row0 = blockIdx.x * 64 + wv * 16;   // 512 blocks x 64 rows = T*N
    f32x4 acc[8];
#pragma unroll
    for (int i = 0; i < 8; i++) acc[i] = (f32x4){0.f, 0.f, 0.f, 0.f};
#pragma unroll
    for (int kt = 0; kt < 2; kt++) {
        const int k = kt * 32 + quad * 8;
        const size_t aoff = (size_t)(row0 + l16) * FF + k;
        bf16x8 a = F32 ? cvt8(xf + aoff) : *(const bf16x8*)(xh + aoff);
#pragma unroll
        for (int nt = 0; nt < 8; nt++) {
            const size_t boff = (size_t)(nt * 16 + l16) * FF + k;
            bf16x8 b = F32 ? cvt8(wf + boff) : *(const bf16x8*)(wh + boff);
            acc[nt] = MFMA(a, b, acc[nt]);
        }
    }
#pragma unroll
    for (int nt = 0; nt < 8; nt++) {
        const int hcol = nt * 16 + l16;
        const float bias = ldf(winb, hcol, F32);
#pragma unroll
        for (int r = 0; r < 4; r++) {
            const int row = row0 + quad * 4 + r;
            xs[(size_t)row * HH + hcol] = f2bf(acc[nt][r] + bias);
        }
    }
}

// ---------------- init carries: h=c=xs[0] (fwd) / xs[T-1] (bwd); also transposed hT ---
__global__ __launch_bounds__(256) void k_init(const short* __restrict__ xs,
                                              short* hf, short* hTf, float* cf,
                                              short* hb, short* hTb, float* cb) {
    const int idx = blockIdx.x * 256 + threadIdx.x;
    const int dir = idx >> 17;
    const int rem = idx & 131071;
    const int row = rem >> 7, hcol = rem & 127;
    const int frame = dir ? (TS - 1) : 0;
    const short v = xs[((size_t)frame * NN + row) * HH + hcol];
    short* h_rm = dir ? hb : hf;
    short* hT   = dir ? hTb : hTf;
    float* c    = dir ? cb : cf;
    h_rm[rem] = v;
    hT[hcol * NN + row] = v;
    c[rem] = bf2f(v);
}

// ---------------- transpose [Wx;Wn;Wh] (384 x 512) -> WcatT (512 x 384) bf16 --------
__global__ __launch_bounds__(256) void k_wprep(const void* __restrict__ Wx,
                                               const void* __restrict__ Wn,
                                               const void* __restrict__ Wh,
                                               short* __restrict__ WcatT,
                                               const int* __restrict__ flag) {
    const int F32 = *flag;
    __shared__ __align__(16) short tile[64][72];
    const int b = blockIdx.x;              // 48 blocks: 8 (n) x 6 (k)
    const int n0 = (b / 6) * 64, k0 = (b % 6) * 64;
    for (int i = threadIdx.x; i < 512; i += 256) {
        const int r = i >> 3, cc = i & 7;
        const int kg = k0 + r;
        const void* m = (kg < 128) ? Wx : (kg < 256 ? Wn : Wh);
        const size_t off = (size_t)(kg & 127) * H4 + n0 + cc * 8;
        *(bf16x8*)&tile[r][cc * 8] =
            F32 ? cvt8((const float*)m + off) : *(const bf16x8*)((const short*)m + off);
    }
    __syncthreads();
    for (int i = threadIdx.x; i < 512; i += 256) {
        const int rr = i >> 3, kk = i & 7;
        bf16x8 o;
#pragma unroll
        for (int j = 0; j < 8; j++) o[j] = tile[kk * 8 + j][rr];
        *(bf16x8*)(WcatT + (size_t)(n0 + rr) * KC + k0 + kk * 8) = o;
    }
}

// ---------------- k_nbr: n = adj[t] @ h_time, split-K x4 into f32 partials ----------
// grid = 512: dir(2) x rowblk(64, 16 rows) x kchunk(4, 256 ks)
__global__ __launch_bounds__(256, 4) void k_nbr(
    const void* __restrict__ adjs,
    const short* __restrict__ hTin_f, const short* __restrict__ hTin_b,
    float* __restrict__ pbuf, int t, const int* __restrict__ flag) {
    const int F32 = *flag;
    const int b = blockIdx.x;
    const int dir = b >> 8;
    const int rb = (b >> 2) & 63;
    const int ch = b & 3;
    const int R = rb * 16, k0 = ch * 256;
    const int frame = dir ? (TS - 1 - t) : t;
    const float* adjf = (const float*)adjs + (size_t)frame * NN * NN;
    const short* adjh = (const short*)adjs + (size_t)frame * NN * NN;
    const short* hT = dir ? hTin_b : hTin_f;

    __shared__ __align__(16) short adjT[16][264];
    const int tid = threadIdx.x;
    {
        const int r = tid >> 4, cs = (tid & 15) * 16;
        const size_t off = (size_t)(R + r) * NN + k0 + cs;
        if (F32) {
            *(bf16x8*)&adjT[r][cs]     = cvt8(adjf + off);
            *(bf16x8*)&adjT[r][cs + 8] = cvt8(adjf + off + 8);
        } else {
            *(bf16x8*)&adjT[r][cs]     = *(const bf16x8*)(adjh + off);
            *(bf16x8*)&adjT[r][cs + 8] = *(const bf16x8*)(adjh + off + 8);
        }
    }
    __syncthreads();

    const int wv = tid >> 6, lane = tid & 63;
    const int quad = lane >> 4, l16 = lane & 15;
    f32x4 an[2];
    an[0] = (f32x4){0.f, 0.f, 0.f, 0.f};
    an[1] = (f32x4){0.f, 0.f, 0.f, 0.f};
#pragma unroll
    for (int kt = 0; kt < 8; kt++) {
        const int kk = kt * 32 + quad * 8;
        bf16x8 a = *(const bf16x8*)&adjT[l16][kk];
#pragma unroll
        for (int nj = 0; nj < 2; nj++) {
            const int hcol = (2 * wv + nj) * 16 + l16;
            bf16x8 bb = *(const bf16x8*)(hT + (size_t)hcol * NN + k0 + kk);
            an[nj] = MFMA(a, bb, an[nj]);
        }
    }
    float* pb = pbuf + (size_t)(dir * 4 + ch) * NN * HH;
#pragma unroll
    for (int nj = 0; nj < 2; nj++) {
        const int hcol = (2 * wv + nj) * 16 + l16;
#pragma unroll
        for (int r = 0; r < 4; r++)
            pb[(size_t)(R + quad * 4 + r) * HH + hcol] = an[nj][r];
    }
}

// ---------------- k_cell: both GNN layers + gating for 16 rows ----------------------
// grid = 128: dir(2) x rowblk(64); 512 threads (8 waves), wave wv owns hcols [wv*16,..)
__global__ __launch_bounds__(512, 2) void k_cell(
    const short* __restrict__ xs,
    const short* __restrict__ WcT_f, const short* __restrict__ WcT_b,
    const void* __restrict__ bias_f, const void* __restrict__ bias_b,
    const float* __restrict__ pbuf,
    short* __restrict__ hf, short* __restrict__ hb,
    short* __restrict__ hTout_f, short* __restrict__ hTout_b,
    float* __restrict__ cf, float* __restrict__ cb, int t,
    const int* __restrict__ flag) {
    const int F32 = *flag;
    const int dir = blockIdx.x >> 6;
    const int R = (blockIdx.x & 63) * 16;
    const int frame = dir ? (TS - 1 - t) : t;
    const short* xs_t = xs + (size_t)frame * NN * HH;
    const short* WcT  = dir ? WcT_b : WcT_f;
    const void* bias  = dir ? bias_b : bias_f;
    short* h_rm       = dir ? hb : hf;
    short* hT_out     = dir ? hTout_b : hTout_f;
    float* c_g        = dir ? cb : cf;
    const int tid = threadIdx.x;

    // Acat: 16 rows; cols [0,128)=xs, [128,256)=n, [256,384)=h (h_time then h_l1)
    __shared__ __align__(16) short Acat[16][392];
    {
        const int r = (tid & 255) >> 4, cc = tid & 15;
        if (tid < 256)
            *(bf16x8*)&Acat[r][cc * 8] =
                *(const bf16x8*)(xs_t + (size_t)(R + r) * HH + cc * 8);
        else
            *(bf16x8*)&Acat[r][256 + cc * 8] =
                *(const bf16x8*)(h_rm + (size_t)(R + r) * HH + cc * 8);
    }
    {
        const int r = tid >> 5, c4 = (tid & 31) * 4;
        const size_t st = (size_t)NN * HH;
        const size_t o = (size_t)(R + r) * HH + c4 + (size_t)dir * 4 * st;
        f32x4 s = *(const f32x4*)(pbuf + o);
        s += *(const f32x4*)(pbuf + o + st);
        s += *(const f32x4*)(pbuf + o + 2 * st);
        s += *(const f32x4*)(pbuf + o + 3 * st);
        s16x4 pk;
#pragma unroll
        for (int j = 0; j < 4; j++) pk[j] = f2bf(s[j]);
        *(s16x4*)&Acat[r][128 + c4] = pk;
    }
    __syncthreads();

    const int wv = tid >> 6, lane = tid & 63;
    const int quad = lane >> 4, l16 = lane & 15;
    const int hcol = wv * 16 + l16;
    const float bi  = ldf(bias, hcol, F32);
    const float bfv = ldf(bias, 128 + hcol, F32);
    const float bo  = ldf(bias, 256 + hcol, F32);
    const float bg  = ldf(bias, 384 + hcol, F32);

    float creg[4];
#pragma unroll
    for (int l = 0; l < 2; l++) {
        f32x4 az[4];
#pragma unroll
        for (int g = 0; g < 4; g++) az[g] = (f32x4){0.f, 0.f, 0.f, 0.f};
#pragma unroll
        for (int kt = 0; kt < 12; kt++) {
            const int kk = kt * 32 + quad * 8;
            bf16x8 a0 = *(const bf16x8*)&Acat[l16][kk];
#pragma unroll
            for (int gt = 0; gt < 4; gt++) {
                bf16x8 bb = *(const bf16x8*)(WcT + (size_t)(gt * 128 + hcol) * KC + kk);
                az[gt] = MFMA(a0, bb, az[gt]);
            }
        }
        short hbf[4];
#pragma unroll
        for (int r = 0; r < 4; r++) {
            const int grow = R + quad * 4 + r;
            const float zi = az[0][r] + bi;
            const float zf = az[1][r] + bfv;
            const float zo = az[2][r] + bo;
            const float zg = az[3][r] + bg;
            const float cold = (l == 0) ? c_g[(size_t)grow * HH + hcol] : creg[r];
            const float cn = sigm(zf) * cold + sigm(zi) * tanhfast(zg);
            creg[r] = cn;
            hbf[r] = f2bf(sigm(zo) * tanhfast(cn));
        }
        if (l == 0) {
            __syncthreads();   // everyone done reading Acat h-region (layer-1 K)
#pragma unroll
            for (int r = 0; r < 4; r++) Acat[quad * 4 + r][256 + hcol] = hbf[r];
            __syncthreads();
        } else {
            s16x4 pk;
#pragma unroll
            for (int r = 0; r < 4; r++) {
                const int grow = R + quad * 4 + r;
                h_rm[(size_t)grow * HH + hcol] = hbf[r];
                c_g[(size_t)grow * HH + hcol] = creg[r];
                pk[r] = hbf[r];
            }
            *(s16x4*)(hT_out + (size_t)hcol * NN + R + quad * 4) = pk;
        }
    }
}

// ---------------- epilogue: y = (cat(hf,hb) @ fc0^T + fc0_b) @ wout^T + wout_b ------
__global__ __launch_bounds__(256) void k_epi(const short* __restrict__ hf,
                                             const short* __restrict__ hb,
                                             const void* __restrict__ fc0_w,
                                             const void* __restrict__ fc0_b,
                                             const void* __restrict__ wout_w,
                                             const void* __restrict__ wout_b,
                                             void* __restrict__ out,
                                             const int* __restrict__ flag) {
    const int F32 = *flag;
    __shared__ float v[256];
    const int tid = threadIdx.x;
    float a = 0.f;
    for (int j = 0; j < 128; j++) a += ldf(wout_w, j, F32) * ldf(fc0_w, j * 256 + tid, F32);
    v[tid] = a;
    __syncthreads();
    float s0 = ldf(wout_b, 0, F32);
    for (int j = 0; j < 128; j++) s0 += ldf(wout_w, j, F32) * ldf(fc0_b, j, F32);
    const int row = blockIdx.x * 256 + tid;
    float y = s0;
    for (int k = 0; k < 128; k++) y += bf2f(hf[(size_t)row * HH + k]) * v[k];
    for (int k = 0; k < 128; k++) y += bf2f(hb[(size_t)row * HH + k]) * v[128 + k];
    if (F32) ((float*)out)[row] = y;
    else ((short*)out)[row] = f2bf(y);
}

extern "C" void kernel_launch(void* const* d_in, const int* in_sizes, int n_in,
                              void* d_out, int out_size, void* d_ws, size_t ws_size,
                              hipStream_t stream) {
    const void* x      = d_in[0];
    const void* adjs   = d_in[1];
    const void* win_w  = d_in[3];
    const void* win_b  = d_in[4];
    const void* fWx    = d_in[5];
    const void* fWh    = d_in[6];
    const void* fWn    = d_in[7];
    const void* fb     = d_in[8];
    const void* bWx    = d_in[9];
    const void* bWh    = d_in[10];
    const void* bWn    = d_in[11];
    const void* bb     = d_in[12];
    const void* fc0_w  = d_in[13];
    const void* fc0_b  = d_in[14];
    const void* wout_w = d_in[15];
    const void* wout_b = d_in[16];

    char* ws = (char*)d_ws;
    size_t off = 0;
    auto alloc = [&](size_t bytes) -> void* {
        void* p = ws + off;
        off += (bytes + 255) & ~(size_t)255;
        return p;
    };
    int*   flag    = (int*)alloc(256);
    short* xs      = (short*)alloc((size_t)TS * NN * HH * 2);
    short* WcatT_f = (short*)alloc((size_t)H4 * KC * 2);
    short* WcatT_b = (short*)alloc((size_t)H4 * KC * 2);
    short* hf      = (short*)alloc((size_t)NN * HH * 2);
    short* hb      = (short*)alloc((size_t)NN * HH * 2);
    short* hTf0    = (short*)alloc((size_t)HH * NN * 2);
    short* hTf1    = (short*)alloc((size_t)HH * NN * 2);
    short* hTb0    = (short*)alloc((size_t)HH * NN * 2);
    short* hTb1    = (short*)alloc((size_t)HH * NN * 2);
    float* cf      = (float*)alloc((size_t)NN * HH * 4);
    float* cb      = (float*)alloc((size_t)NN * HH * 4);
    float* pbuf    = (float*)alloc((size_t)2 * 4 * NN * HH * 4);

    hipLaunchKernelGGL(k_detect, dim3(1), dim3(64), 0, stream, (const unsigned int*)x, flag);
    hipLaunchKernelGGL(k_wprep, dim3(48), dim3(256), 0, stream, fWx, fWn, fWh, WcatT_f, flag);
    hipLaunchKernelGGL(k_wprep, dim3(48), dim3(256), 0, stream, bWx, bWn, bWh, WcatT_b, flag);
    hipLaunchKernelGGL(k_xs, dim3(512), dim3(256), 0, stream, x, win_w, win_b, xs, flag);
    hipLaunchKernelGGL(k_init, dim3(1024), dim3(256), 0, stream, xs, hf, hTf0, cf, hb, hTb0, cb);
    for (int t = 0; t < TS; t++) {
        const short* hin_f = (t & 1) ? hTf1 : hTf0;
        short* hout_f      = (t & 1) ? hTf0 : hTf1;
        const short* hin_b = (t & 1) ? hTb1 : hTb0;
        short* hout_b      = (t & 1) ? hTb0 : hTb1;
        hipLaunchKernelGGL(k_nbr, dim3(512), dim3(256), 0, stream, adjs,
                           hin_f, hin_b, pbuf, t, flag);
        hipLaunchKernelGGL(k_cell, dim3(128), dim3(512), 0, stream, xs,
                           WcatT_f, WcatT_b, fb, bb, pbuf, hf, hb,
                           hout_f, hout_b, cf, cb, t, flag);
    }
    hipLaunchKernelGGL(k_epi, dim3(4), dim3(256), 0, stream, hf, hb, fc0_w, fc0_b,
                       wout_w, wout_b, d_out, flag);
}

// Round 4
// 1160.077 us; speedup vs baseline: 1.6022x; 1.1887x over previous
//
#include <hip/hip_runtime.h>
#include <hip/hip_cooperative_groups.h>

namespace cg = cooperative_groups;

#define TS 32
#define NN 1024
#define FF 64
#define HH 128
#define H4 512
#define KC 384   // 3*HH, concat K for [Wx;Wn;Wh]

typedef __attribute__((ext_vector_type(8))) short bf16x8;
typedef __attribute__((ext_vector_type(4))) float f32x4;
typedef __attribute__((ext_vector_type(4))) short s16x4;

static __device__ __forceinline__ float bf2f(short s) {
    union { unsigned int u; float f; } v;
    v.u = ((unsigned int)(unsigned short)s) << 16;
    return v.f;
}
static __device__ __forceinline__ short f2bf(float x) {   // RTNE
    union { float f; unsigned int u; } v; v.f = x;
    unsigned int r = v.u + 0x7fffu + ((v.u >> 16) & 1u);
    return (short)(r >> 16);
}
static __device__ __forceinline__ bf16x8 cvt8(const float* p) {
    f32x4 lo = *(const f32x4*)p;
    f32x4 hi = *(const f32x4*)(p + 4);
    bf16x8 r;
#pragma unroll
    for (int j = 0; j < 4; j++) { r[j] = f2bf(lo[j]); r[4 + j] = f2bf(hi[j]); }
    return r;
}
static __device__ __forceinline__ float sigm(float x) { return 1.0f / (1.0f + __expf(-x)); }
static __device__ __forceinline__ float tanhfast(float x) { return 1.0f - 2.0f / (__expf(2.0f * x) + 1.0f); }
static __device__ __forceinline__ f32x4 MFMA(bf16x8 a, bf16x8 b, f32x4 c) {
    return __builtin_amdgcn_mfma_f32_16x16x32_bf16(a, b, c, 0, 0, 0);
}

// ------- transpose [Wx;Wn;Wh] (384x512 f32) -> WcatT (512x384 bf16), both dirs ------
__global__ __launch_bounds__(256) void k_wprep2(const float* __restrict__ fWx,
                                                const float* __restrict__ fWn,
                                                const float* __restrict__ fWh,
                                                const float* __restrict__ bWx,
                                                const float* __restrict__ bWn,
                                                const float* __restrict__ bWh,
                                                short* __restrict__ WcatT_f,
                                                short* __restrict__ WcatT_b) {
    __shared__ __align__(16) short tile[64][72];
    const int b = blockIdx.x;              // 96 blocks: 2 halves x 8 (n) x 6 (k)
    const int half = b / 48, sub = b % 48;
    const float* Wx = half ? bWx : fWx;
    const float* Wn = half ? bWn : fWn;
    const float* Wh = half ? bWh : fWh;
    short* dst = half ? WcatT_b : WcatT_f;
    const int n0 = (sub / 6) * 64, k0 = (sub % 6) * 64;
    for (int i = threadIdx.x; i < 512; i += 256) {
        const int r = i >> 3, cc = i & 7;
        const int kg = k0 + r;
        const float* m = (kg < 128) ? Wx : (kg < 256 ? Wn : Wh);
        *(bf16x8*)&tile[r][cc * 8] = cvt8(m + (size_t)(kg & 127) * H4 + n0 + cc * 8);
    }
    __syncthreads();
    for (int i = threadIdx.x; i < 512; i += 256) {
        const int rr = i >> 3, kk = i & 7;
        bf16x8 o;
#pragma unroll
        for (int j = 0; j < 8; j++) o[j] = tile[kk * 8 + j][rr];
        *(bf16x8*)(dst + (size_t)(n0 + rr) * KC + k0 + kk * 8) = o;
    }
}

// ------- xs = x @ Win^T + Win_b (bf16 out); folds hT0 init for frames 0 / T-1 -------
__global__ __launch_bounds__(256) void k_xs(const float* __restrict__ x,
                                            const float* __restrict__ winw,
                                            const float* __restrict__ winb,
                                            short* __restrict__ xs,
                                            short* __restrict__ hTf0,
                                            short* __restrict__ hTb0) {
    const int wv = threadIdx.x >> 6, lane = threadIdx.x & 63;
    const int quad = lane >> 4, l16 = lane & 15;
    const int row0 = blockIdx.x * 64 + wv * 16;   // 512 blocks x 64 rows = T*N
    f32x4 acc[8];
#pragma unroll
    for (int i = 0; i < 8; i++) acc[i] = (f32x4){0.f, 0.f, 0.f, 0.f};
#pragma unroll
    for (int kt = 0; kt < 2; kt++) {
        const int k = kt * 32 + quad * 8;
        bf16x8 a = cvt8(x + (size_t)(row0 + l16) * FF + k);
#pragma unroll
        for (int nt = 0; nt < 8; nt++) {
            bf16x8 b = cvt8(winw + (size_t)(nt * 16 + l16) * FF + k);
            acc[nt] = MFMA(a, b, acc[nt]);
        }
    }
#pragma unroll
    for (int nt = 0; nt < 8; nt++) {
        const int hcol = nt * 16 + l16;
        const float bias = winb[hcol];
#pragma unroll
        for (int r = 0; r < 4; r++) {
            const int row = row0 + quad * 4 + r;
            const short v = f2bf(acc[nt][r] + bias);
            xs[(size_t)row * HH + hcol] = v;
            const int frame = row >> 10, nrow = row & 1023;
            if (frame == 0) hTf0[(size_t)hcol * NN + nrow] = v;
            else if (frame == TS - 1) hTb0[(size_t)hcol * NN + nrow] = v;
        }
    }
}

// ------- persistent: all 32 timesteps, both dirs, both layers, + fused epilogue -----
// 128 blocks x 512 thr. block = (dir, 16 rows). wave wv owns h-cols [wv*16, wv*16+16).
__global__ __launch_bounds__(512, 2) void k_main(
    const float* __restrict__ adjs, const short* __restrict__ xs,
    const short* __restrict__ WcT_f, const short* __restrict__ WcT_b,
    const float* __restrict__ bias_f, const float* __restrict__ bias_b,
    short* __restrict__ hTf0, short* __restrict__ hTf1,
    short* __restrict__ hTb0, short* __restrict__ hTb1,
    const float* __restrict__ fc0_w, const float* __restrict__ fc0_b,
    const float* __restrict__ wout_w, const float* __restrict__ wout_b,
    float* __restrict__ out) {
    cg::grid_group grid = cg::this_grid();
    __shared__ __align__(16) short wg[12 * 4 * HH * 8];   // gate-g weights, 96 KB
    __shared__ __align__(16) short adjT[16][1032];        // 33 KB (+8 pad)
    __shared__ __align__(16) short Acat[16][392];         // [xs | n | h], 12.5 KB
    __shared__ float vsh[256];
    __shared__ float s0sh;

    const int tid = threadIdx.x;
    const int wv = tid >> 6, lane = tid & 63, quad = lane >> 4, l16 = lane & 15;
    const int dir = blockIdx.x >> 6, rb = blockIdx.x & 63, R = rb * 16;
    const short* WcT  = dir ? WcT_b : WcT_f;
    const float* bias = dir ? bias_b : bias_f;
    short* hT0 = dir ? hTb0 : hTf0;
    short* hT1 = dir ? hTb1 : hTf1;
    const int hcol = wv * 16 + l16;

    // gates i,f,o: B-fragments resident in registers for the whole kernel (144 VGPRs)
    bf16x8 wr[3][12];
#pragma unroll
    for (int gt = 0; gt < 3; gt++)
#pragma unroll
        for (int kt = 0; kt < 12; kt++)
            wr[gt][kt] = *(const bf16x8*)(WcT + (size_t)(gt * HH + hcol) * KC + kt * 32 + quad * 8);
    // gate g: resident in LDS. layout [kt][quad][hcol] of bf16x8 — i*8 linear.
    for (int i = tid; i < 6144; i += 512) {
        const int kt = i >> 9, rem = i & 511, qd = rem >> 7, hc = rem & 127;
        *(bf16x8*)&wg[(size_t)i * 8] =
            *(const bf16x8*)(WcT + (size_t)(3 * HH + hc) * KC + kt * 32 + qd * 8);
    }
    const float bi  = bias[hcol];
    const float bf_ = bias[HH + hcol];
    const float bo  = bias[2 * HH + hcol];
    const float bg_ = bias[3 * HH + hcol];

    // init: h_time region of Acat + c carry from xs[frame0]
    const int frame0 = dir ? (TS - 1) : 0;
    if (tid < 256) {
        const int r = tid >> 4, cc = tid & 15;
        *(bf16x8*)&Acat[r][256 + cc * 8] =
            *(const bf16x8*)(xs + ((size_t)frame0 * NN + R + r) * HH + cc * 8);
    }
    __syncthreads();
    float creg[4];
#pragma unroll
    for (int r = 0; r < 4; r++) creg[r] = bf2f(Acat[quad * 4 + r][256 + hcol]);

    for (int t = 0; t < TS; t++) {
        const int frame = dir ? (TS - 1 - t) : t;
        const float* adj_t = adjs + (size_t)frame * NN * NN;
        const short* xs_t  = xs + (size_t)frame * NN * HH;
        const short* hTi = (t & 1) ? hT1 : hT0;
        short* hTo       = (t & 1) ? hT0 : hT1;

        // stage xs_t rows -> Acat[:,0:128]   (prev-iter readers fenced by last barrier)
        if (tid < 256) {
            const int r = tid >> 4, cc = tid & 15;
            *(bf16x8*)&Acat[r][cc * 8] =
                *(const bf16x8*)(xs_t + (size_t)(R + r) * HH + cc * 8);
        }
        // stage adj rows f32->bf16 -> adjT
        {
            const int r = tid >> 5, c0 = (tid & 31) * 32;
            const float* src = adj_t + (size_t)(R + r) * NN + c0;
#pragma unroll
            for (int j = 0; j < 4; j++)
                *(bf16x8*)&adjT[r][c0 + j * 8] = cvt8(src + j * 8);
        }
        grid.sync();   // hT(t-1) globally visible; also block barrier for staging

        // phase n: n[16,128] = adj_rows @ h_time  (B straight from transposed hT in L2)
        f32x4 an = (f32x4){0.f, 0.f, 0.f, 0.f};
#pragma unroll
        for (int kt = 0; kt < 32; kt++) {
            bf16x8 a = *(const bf16x8*)&adjT[l16][kt * 32 + quad * 8];
            bf16x8 b = *(const bf16x8*)(hTi + (size_t)hcol * NN + kt * 32 + quad * 8);
            an = MFMA(a, b, an);
        }
#pragma unroll
        for (int r = 0; r < 4; r++) Acat[quad * 4 + r][HH + hcol] = f2bf(an[r]);
        __syncthreads();   // n complete before gate K-loops

        // two GNN layers; weights stay in regs/LDS; c in regs
#pragma unroll
        for (int l = 0; l < 2; l++) {
            f32x4 az0 = (f32x4){0.f, 0.f, 0.f, 0.f};
            f32x4 az1 = az0, az2 = az0, az3 = az0;
#pragma unroll
            for (int kt = 0; kt < 12; kt++) {
                bf16x8 a = *(const bf16x8*)&Acat[l16][kt * 32 + quad * 8];
                az0 = MFMA(a, wr[0][kt], az0);
                az1 = MFMA(a, wr[1][kt], az1);
                az2 = MFMA(a, wr[2][kt], az2);
                bf16x8 b3 = *(const bf16x8*)&wg[((size_t)kt * 512 + quad * 128 + hcol) * 8];
                az3 = MFMA(a, b3, az3);
            }
            short hbf[4];
#pragma unroll
            for (int r = 0; r < 4; r++) {
                const float cn = sigm(az1[r] + bf_) * creg[r]
                               + sigm(az0[r] + bi) * tanhfast(az3[r] + bg_);
                creg[r] = cn;
                hbf[r] = f2bf(sigm(az2[r] + bo) * tanhfast(cn));
            }
            __syncthreads();   // all waves done reading Acat[:,256:384]
#pragma unroll
            for (int r = 0; r < 4; r++) Acat[quad * 4 + r][256 + hcol] = hbf[r];
            if (l == 0) {
                __syncthreads();   // h_l1 visible for layer-2 K-loop
            } else {
                // h_l2 -> Acat (next step's h_time) and transposed global carry
                s16x4 pk;
#pragma unroll
                for (int r = 0; r < 4; r++) pk[r] = hbf[r];
                *(s16x4*)(hTo + (size_t)hcol * NN + R + quad * 4) = pk;
            }
        }
    }

    // ---- fused epilogue: y = hf @ v[0:128] + hb @ v[128:256] + s0 ------------------
    grid.sync();   // dir-1 final hT (in hT0 side after t=31) visible
    if (dir == 0) {
        for (int j = tid; j < 256; j += 512) {
            float a = 0.f;
            for (int i = 0; i < HH; i++) a += wout_w[i] * fc0_w[(size_t)i * 256 + j];
            vsh[j] = a;
        }
        if (tid == 0) {
            float s = wout_b[0];
            for (int i = 0; i < HH; i++) s += wout_w[i] * fc0_b[i];
            s0sh = s;
        }
        __syncthreads();
        const int r = tid >> 5, j = tid & 31;   // 16 rows x 32 lanes
        float p = 0.f;
        for (int k = j; k < HH; k += 32)
            p += bf2f(Acat[r][256 + k]) * vsh[k]
               + bf2f(hTb0[(size_t)k * NN + R + r]) * vsh[HH + k];
#pragma unroll
        for (int off = 16; off > 0; off >>= 1) p += __shfl_down(p, off, 32);
        if (j == 0) out[R + r] = p + s0sh;
    }
}

extern "C" void kernel_launch(void* const* d_in, const int* in_sizes, int n_in,
                              void* d_out, int out_size, void* d_ws, size_t ws_size,
                              hipStream_t stream) {
    const float* x      = (const float*)d_in[0];
    const float* adjs   = (const float*)d_in[1];
    const float* win_w  = (const float*)d_in[3];
    const float* win_b  = (const float*)d_in[4];
    const float* fWx    = (const float*)d_in[5];
    const float* fWh    = (const float*)d_in[6];
    const float* fWn    = (const float*)d_in[7];
    const float* fb     = (const float*)d_in[8];
    const float* bWx    = (const float*)d_in[9];
    const float* bWh    = (const float*)d_in[10];
    const float* bWn    = (const float*)d_in[11];
    const float* bb     = (const float*)d_in[12];
    const float* fc0_w  = (const float*)d_in[13];
    const float* fc0_b  = (const float*)d_in[14];
    const float* wout_w = (const float*)d_in[15];
    const float* wout_b = (const float*)d_in[16];

    char* ws = (char*)d_ws;
    size_t off = 0;
    auto alloc = [&](size_t bytes) -> void* {
        void* p = ws + off;
        off += (bytes + 255) & ~(size_t)255;
        return p;
    };
    short* xs      = (short*)alloc((size_t)TS * NN * HH * 2);
    short* WcatT_f = (short*)alloc((size_t)H4 * KC * 2);
    short* WcatT_b = (short*)alloc((size_t)H4 * KC * 2);
    short* hTf0    = (short*)alloc((size_t)HH * NN * 2);
    short* hTf1    = (short*)alloc((size_t)HH * NN * 2);
    short* hTb0    = (short*)alloc((size_t)HH * NN * 2);
    short* hTb1    = (short*)alloc((size_t)HH * NN * 2);
    float* outp    = (float*)d_out;

    hipLaunchKernelGGL(k_wprep2, dim3(96), dim3(256), 0, stream,
                       fWx, fWn, fWh, bWx, bWn, bWh, WcatT_f, WcatT_b);
    hipLaunchKernelGGL(k_xs, dim3(512), dim3(256), 0, stream,
                       x, win_w, win_b, xs, hTf0, hTb0);

    void* args[] = {
        (void*)&adjs, (void*)&xs, (void*)&WcatT_f, (void*)&WcatT_b,
        (void*)&fb, (void*)&bb,
        (void*)&hTf0, (void*)&hTf1, (void*)&hTb0, (void*)&hTb1,
        (void*)&fc0_w, (void*)&fc0_b, (void*)&wout_w, (void*)&wout_b,
        (void*)&outp,
    };
    hipLaunchCooperativeKernel((void*)k_main, dim3(128), dim3(512), args, 0, stream);
}

// Round 5
// 1127.934 us; speedup vs baseline: 1.6479x; 1.0285x over previous
//
#include <hip/hip_runtime.h>

#define TS 32
#define NN 1024
#define FF 64
#define HH 128
#define H4 512
#define KC 384    // 3*HH
#define NBLK 64   // blocks per direction
#define ASTR 1026 // adjT row stride (shorts): 513 dwords == 1 mod 32 -> conflict-free

typedef __attribute__((ext_vector_type(8))) short bf16x8;
typedef __attribute__((ext_vector_type(4))) float f32x4;
typedef __attribute__((ext_vector_type(4))) short s16x4;

static __device__ __forceinline__ float bf2f(short s) {
    union { unsigned int u; float f; } v;
    v.u = ((unsigned int)(unsigned short)s) << 16;
    return v.f;
}
static __device__ __forceinline__ short f2bf(float x) {   // RTNE
    union { float f; unsigned int u; } v; v.f = x;
    unsigned int r = v.u + 0x7fffu + ((v.u >> 16) & 1u);
    return (short)(r >> 16);
}
static __device__ __forceinline__ bf16x8 cvt8(const float* p) {
    f32x4 lo = *(const f32x4*)p;
    f32x4 hi = *(const f32x4*)(p + 4);
    bf16x8 r;
#pragma unroll
    for (int j = 0; j < 4; j++) { r[j] = f2bf(lo[j]); r[4 + j] = f2bf(hi[j]); }
    return r;
}
static __device__ __forceinline__ bf16x8 cvt8v(f32x4 lo, f32x4 hi) {
    bf16x8 r;
#pragma unroll
    for (int j = 0; j < 4; j++) { r[j] = f2bf(lo[j]); r[4 + j] = f2bf(hi[j]); }
    return r;
}
static __device__ __forceinline__ float sigm(float x) { return 1.0f / (1.0f + __expf(-x)); }
static __device__ __forceinline__ float tanhfast(float x) { return 1.0f - 2.0f / (__expf(2.0f * x) + 1.0f); }
static __device__ __forceinline__ f32x4 MFMA(bf16x8 a, bf16x8 b, f32x4 c) {
    return __builtin_amdgcn_mfma_f32_16x16x32_bf16(a, b, c, 0, 0, 0);
}

// ---- fused prologue: xs-GEMM (blocks 0..511), weight transpose (512..607),
// ---- fc0/wout fold + counter/out zero (block 608)
__global__ __launch_bounds__(256) void k_pre(
    const float* __restrict__ x, const float* __restrict__ winw,
    const float* __restrict__ winb,
    const float* __restrict__ fWx, const float* __restrict__ fWn,
    const float* __restrict__ fWh,
    const float* __restrict__ bWx, const float* __restrict__ bWn,
    const float* __restrict__ bWh,
    const float* __restrict__ fc0_w, const float* __restrict__ fc0_b,
    const float* __restrict__ wout_w, const float* __restrict__ wout_b,
    short* __restrict__ xs, short* __restrict__ hTf0, short* __restrict__ hTb0,
    short* __restrict__ WcatT_f, short* __restrict__ WcatT_b,
    float* __restrict__ vsh_g, unsigned int* __restrict__ cnt,
    float* __restrict__ out) {
    const int b = blockIdx.x;
    const int tid = threadIdx.x;
    if (b < 512) {
        // xs = x @ Win^T + b; also init transposed h carries for frames 0 / T-1
        const int wv = tid >> 6, lane = tid & 63;
        const int quad = lane >> 4, l16 = lane & 15;
        const int row0 = b * 64 + wv * 16;
        f32x4 acc[8];
#pragma unroll
        for (int i = 0; i < 8; i++) acc[i] = (f32x4){0.f, 0.f, 0.f, 0.f};
#pragma unroll
        for (int kt = 0; kt < 2; kt++) {
            const int k = kt * 32 + quad * 8;
            bf16x8 a = cvt8(x + (size_t)(row0 + l16) * FF + k);
#pragma unroll
            for (int nt = 0; nt < 8; nt++) {
                bf16x8 bb = cvt8(winw + (size_t)(nt * 16 + l16) * FF + k);
                acc[nt] = MFMA(a, bb, acc[nt]);
            }
        }
#pragma unroll
        for (int nt = 0; nt < 8; nt++) {
            const int hcol = nt * 16 + l16;
            const float bias = winb[hcol];
#pragma unroll
            for (int r = 0; r < 4; r++) {
                const int row = row0 + quad * 4 + r;
                const short v = f2bf(acc[nt][r] + bias);
                xs[(size_t)row * HH + hcol] = v;
                const int frame = row >> 10, nrow = row & 1023;
                if (frame == 0) hTf0[(size_t)hcol * NN + nrow] = v;
                else if (frame == TS - 1) hTb0[(size_t)hcol * NN + nrow] = v;
            }
        }
    } else if (b < 608) {
        __shared__ __align__(16) short tile[64][72];
        const int b2 = b - 512;
        const int half = b2 / 48, sub = b2 % 48;
        const float* Wx = half ? bWx : fWx;
        const float* Wn = half ? bWn : fWn;
        const float* Wh = half ? bWh : fWh;
        short* dst = half ? WcatT_b : WcatT_f;
        const int n0 = (sub / 6) * 64, k0 = (sub % 6) * 64;
        for (int i = tid; i < 512; i += 256) {
            const int r = i >> 3, cc = i & 7;
            const int kg = k0 + r;
            const float* m = (kg < 128) ? Wx : (kg < 256 ? Wn : Wh);
            *(bf16x8*)&tile[r][cc * 8] = cvt8(m + (size_t)(kg & 127) * H4 + n0 + cc * 8);
        }
        __syncthreads();
        for (int i = tid; i < 512; i += 256) {
            const int rr = i >> 3, kk = i & 7;
            bf16x8 o;
#pragma unroll
            for (int j = 0; j < 8; j++) o[j] = tile[kk * 8 + j][rr];
            *(bf16x8*)(dst + (size_t)(n0 + rr) * KC + k0 + kk * 8) = o;
        }
    } else {
        // v[j] = sum_i wout_w[i]*fc0_w[i*256+j]; s0 = wout_b + wout_w . fc0_b
        float a = 0.f;
        for (int i = 0; i < HH; i++) a += wout_w[i] * fc0_w[(size_t)i * 256 + tid];
        vsh_g[tid] = a;
        if (tid == 0) {
            float s = wout_b[0];
            for (int i = 0; i < HH; i++) s += wout_w[i] * fc0_b[i];
            vsh_g[256] = s;
            cnt[0] = 0u;
            cnt[1] = 0u;
        }
        for (int i = tid; i < NN; i += 256) out[i] = 0.f;
    }
}

// ---- persistent main kernel: 128 blocks x 512 thr, block = (dir, 16 rows) --------
__global__ __launch_bounds__(512, 2) void k_main(
    const float* __restrict__ adjs, const short* __restrict__ xs,
    const short* __restrict__ WcT_f, const short* __restrict__ WcT_b,
    const float* __restrict__ bias_f, const float* __restrict__ bias_b,
    short* __restrict__ hTf0, short* __restrict__ hTf1,
    short* __restrict__ hTb0, short* __restrict__ hTb1,
    const float* __restrict__ vsh_g, unsigned int* __restrict__ cnt,
    float* __restrict__ out) {
    __shared__ __align__(16) short wg[12 * 4 * HH * 8];   // gate-g weights, 96 KB
    __shared__ __align__(16) short adjT[16 * ASTR];       // ~32 KB, conflict-free
    __shared__ __align__(16) short Acat[16][392];         // [xs | n | h]

    const int tid = threadIdx.x;
    const int wv = tid >> 6, lane = tid & 63, quad = lane >> 4, l16 = lane & 15;
    const int dir = blockIdx.x >> 6, R = (blockIdx.x & 63) * 16;
    const short* WcT  = dir ? WcT_b : WcT_f;
    const float* bias = dir ? bias_b : bias_f;
    short* hT0 = dir ? hTb0 : hTf0;
    short* hT1 = dir ? hTb1 : hTf1;
    unsigned int* mycnt = cnt + dir;
    const int hcol = wv * 16 + l16;

    // gates i,f,o fragments (compiler may cache in regs or re-stream from warm L2)
    bf16x8 wr0[12], wr1[12], wr2[12];
#pragma unroll
    for (int kt = 0; kt < 12; kt++) {
        wr0[kt] = *(const bf16x8*)(WcT + (size_t)(0 * HH + hcol) * KC + kt * 32 + quad * 8);
        wr1[kt] = *(const bf16x8*)(WcT + (size_t)(1 * HH + hcol) * KC + kt * 32 + quad * 8);
        wr2[kt] = *(const bf16x8*)(WcT + (size_t)(2 * HH + hcol) * KC + kt * 32 + quad * 8);
    }
    // gate g in LDS: [kt][quad][hcol] bf16x8 granules
    for (int i = tid; i < 6144; i += 512) {
        const int kt = i >> 9, rem = i & 511, qd = rem >> 7, hc = rem & 127;
        *(bf16x8*)&wg[(size_t)i * 8] =
            *(const bf16x8*)(WcT + (size_t)(3 * HH + hc) * KC + kt * 32 + qd * 8);
    }
    const float bi  = bias[hcol];
    const float bf_ = bias[HH + hcol];
    const float bo  = bias[2 * HH + hcol];
    const float bg_ = bias[3 * HH + hcol];

    const int frame0 = dir ? (TS - 1) : 0;
    if (tid < 256) {
        const int r = tid >> 4, cc = tid & 15;
        *(bf16x8*)&Acat[r][256 + cc * 8] =
            *(const bf16x8*)(xs + ((size_t)frame0 * NN + R + r) * HH + cc * 8);
    }
    // prologue: stage adjT(frame0). lane map: row=tid&15, colgroup=tid>>4 (bank-clean)
    const int ar = tid & 15, ac = tid >> 4;
    {
        const float* asrc = adjs + (size_t)frame0 * NN * NN + (size_t)(R + ar) * NN + ac * 32;
        f32x4 p0[8];
#pragma unroll
        for (int j = 0; j < 8; j++) p0[j] = *(const f32x4*)(asrc + j * 4);
#pragma unroll
        for (int j = 0; j < 4; j++)
            *(bf16x8*)&adjT[ar * ASTR + ac * 32 + j * 8] = cvt8v(p0[2 * j], p0[2 * j + 1]);
    }
    __syncthreads();
    float creg[4];
#pragma unroll
    for (int r = 0; r < 4; r++) creg[r] = bf2f(Acat[quad * 4 + r][256 + hcol]);

    f32x4 pf[8];
    for (int t = 0; t < TS; t++) {
        const int frame = dir ? (TS - 1 - t) : t;
        const short* xs_t = xs + (size_t)frame * NN * HH;
        const short* hTi = (t & 1) ? hT1 : hT0;
        short* hTo       = (t & 1) ? hT0 : hT1;

        // A: stage xs_t rows (prev-iter readers fenced by arrive's __syncthreads)
        if (tid < 256) {
            const int r = tid >> 4, cc = tid & 15;
            *(bf16x8*)&Acat[r][cc * 8] =
                *(const bf16x8*)(xs_t + (size_t)(R + r) * HH + cc * 8);
        }
        // B: prefetch next frame's adj rows into registers (hides HBM under spin)
        if (t < TS - 1) {
            const int nf = dir ? (TS - 2 - t) : (t + 1);
            const float* asrc = adjs + (size_t)nf * NN * NN + (size_t)(R + ar) * NN + ac * 32;
#pragma unroll
            for (int j = 0; j < 8; j++) pf[j] = *(const f32x4*)(asrc + j * 4);
        }
        // C: wait for all my-dir blocks to have finished step t-1
        if (tid == 0) {
            const unsigned int tgt = (unsigned int)(NBLK * t);
            while (__hip_atomic_load(mycnt, __ATOMIC_RELAXED, __HIP_MEMORY_SCOPE_AGENT) < tgt)
                __builtin_amdgcn_s_sleep(2);
        }
        __syncthreads();
        asm volatile("" ::: "memory");

        // D: phase n = adj_rows @ h_time; hT via relaxed agent atomics (coherent)
        f32x4 an = (f32x4){0.f, 0.f, 0.f, 0.f};
        const unsigned long long* hrow =
            (const unsigned long long*)(hTi + (size_t)hcol * NN);
#pragma unroll
        for (int kt = 0; kt < 32; kt++) {
            bf16x8 a = *(const bf16x8*)&adjT[l16 * ASTR + kt * 32 + quad * 8];
            union { unsigned long long u[2]; bf16x8 v; } bu;
            bu.u[0] = __hip_atomic_load((unsigned long long*)(hrow + kt * 8 + quad * 2),
                                        __ATOMIC_RELAXED, __HIP_MEMORY_SCOPE_AGENT);
            bu.u[1] = __hip_atomic_load((unsigned long long*)(hrow + kt * 8 + quad * 2 + 1),
                                        __ATOMIC_RELAXED, __HIP_MEMORY_SCOPE_AGENT);
            an = MFMA(a, bu.v, an);
        }
#pragma unroll
        for (int r = 0; r < 4; r++) Acat[quad * 4 + r][HH + hcol] = f2bf(an[r]);
        __syncthreads();   // E: n visible; all phase-n adjT reads done

        // F: write next step's adjT from prefetched regs
        if (t < TS - 1) {
#pragma unroll
            for (int j = 0; j < 4; j++)
                *(bf16x8*)&adjT[ar * ASTR + ac * 32 + j * 8] = cvt8v(pf[2 * j], pf[2 * j + 1]);
        }

        // G/H: two GNN layers
#pragma unroll
        for (int l = 0; l < 2; l++) {
            f32x4 az0 = (f32x4){0.f, 0.f, 0.f, 0.f};
            f32x4 az1 = az0, az2 = az0, az3 = az0;
#pragma unroll
            for (int kt = 0; kt < 12; kt++) {
                bf16x8 a = *(const bf16x8*)&Acat[l16][kt * 32 + quad * 8];
                az0 = MFMA(a, wr0[kt], az0);
                az1 = MFMA(a, wr1[kt], az1);
                az2 = MFMA(a, wr2[kt], az2);
                bf16x8 b3 = *(const bf16x8*)&wg[((size_t)kt * 512 + quad * 128 + hcol) * 8];
                az3 = MFMA(a, b3, az3);
            }
            short hbf[4];
#pragma unroll
            for (int r = 0; r < 4; r++) {
                const float cn = sigm(az1[r] + bf_) * creg[r]
                               + sigm(az0[r] + bi) * tanhfast(az3[r] + bg_);
                creg[r] = cn;
                hbf[r] = f2bf(sigm(az2[r] + bo) * tanhfast(cn));
            }
            __syncthreads();   // all waves done reading Acat h-region
#pragma unroll
            for (int r = 0; r < 4; r++) Acat[quad * 4 + r][256 + hcol] = hbf[r];
            if (l == 0) {
                __syncthreads();
            } else {
                union { s16x4 v; unsigned long long u; } pk;
#pragma unroll
                for (int r = 0; r < 4; r++) pk.v[r] = hbf[r];
                __hip_atomic_store(
                    (unsigned long long*)(hTo + (size_t)hcol * NN + R + quad * 4),
                    pk.u, __ATOMIC_RELAXED, __HIP_MEMORY_SCOPE_AGENT);
            }
        }
        // I: arrive — own stores done, block-wide, then one release RMW
        asm volatile("s_waitcnt vmcnt(0)" ::: "memory");
        __syncthreads();
        if (tid == 0)
            __hip_atomic_fetch_add(mycnt, 1u, __ATOMIC_RELEASE, __HIP_MEMORY_SCOPE_AGENT);
    }

    // epilogue: each dir contributes its half of y via f32 atomicAdd (out zeroed)
    if (tid < 256) {
        const int r = tid >> 4, j = tid & 15;
        float p = 0.f;
        for (int k = j * 8; k < j * 8 + 8; k++)
            p += bf2f(Acat[r][256 + k]) * vsh_g[dir * HH + k];
#pragma unroll
        for (int off = 8; off; off >>= 1) p += __shfl_down(p, off, 16);
        if (j == 0) atomicAdd(&out[R + r], p + (dir ? 0.f : vsh_g[256]));
    }
}

extern "C" void kernel_launch(void* const* d_in, const int* in_sizes, int n_in,
                              void* d_out, int out_size, void* d_ws, size_t ws_size,
                              hipStream_t stream) {
    const float* x      = (const float*)d_in[0];
    const float* adjs   = (const float*)d_in[1];
    const float* win_w  = (const float*)d_in[3];
    const float* win_b  = (const float*)d_in[4];
    const float* fWx    = (const float*)d_in[5];
    const float* fWh    = (const float*)d_in[6];
    const float* fWn    = (const float*)d_in[7];
    const float* fb     = (const float*)d_in[8];
    const float* bWx    = (const float*)d_in[9];
    const float* bWh    = (const float*)d_in[10];
    const float* bWn    = (const float*)d_in[11];
    const float* bb     = (const float*)d_in[12];
    const float* fc0_w  = (const float*)d_in[13];
    const float* fc0_b  = (const float*)d_in[14];
    const float* wout_w = (const float*)d_in[15];
    const float* wout_b = (const float*)d_in[16];

    char* ws = (char*)d_ws;
    size_t off = 0;
    auto alloc = [&](size_t bytes) -> void* {
        void* p = ws + off;
        off += (bytes + 255) & ~(size_t)255;
        return p;
    };
    short* xs      = (short*)alloc((size_t)TS * NN * HH * 2);
    short* WcatT_f = (short*)alloc((size_t)H4 * KC * 2);
    short* WcatT_b = (short*)alloc((size_t)H4 * KC * 2);
    short* hTf0    = (short*)alloc((size_t)HH * NN * 2);
    short* hTf1    = (short*)alloc((size_t)HH * NN * 2);
    short* hTb0    = (short*)alloc((size_t)HH * NN * 2);
    short* hTb1    = (short*)alloc((size_t)HH * NN * 2);
    float* vsh_g   = (float*)alloc(257 * 4);
    unsigned int* cnt = (unsigned int*)alloc(256);
    float* outp    = (float*)d_out;

    hipLaunchKernelGGL(k_pre, dim3(609), dim3(256), 0, stream,
                       x, win_w, win_b, fWx, fWn, fWh, bWx, bWn, bWh,
                       fc0_w, fc0_b, wout_w, wout_b,
                       xs, hTf0, hTb0, WcatT_f, WcatT_b, vsh_g, cnt, outp);

    void* args[] = {
        (void*)&adjs, (void*)&xs, (void*)&WcatT_f, (void*)&WcatT_b,
        (void*)&fb, (void*)&bb,
        (void*)&hTf0, (void*)&hTf1, (void*)&hTb0, (void*)&hTb1,
        (void*)&vsh_g, (void*)&cnt, (void*)&outp,
    };
    hipLaunchCooperativeKernel((void*)k_main, dim3(128), dim3(512), args, 0, stream);
}